// Round 1
// 142.482 us; speedup vs baseline: 1.0467x; 1.0467x over previous
//
#include <hip/hip_runtime.h>

#define NUM_BINS 256
#define BATCH 32
#define CHW (3 * 512 * 512)     // elements per batch (== gen_hist row sum, exact)
#define N4 (CHW / 4)            // 196608 float4 per batch
#define BPB 64                  // hist blocks per batch -> 12 float4 iters/thread
#define ITERS (N4 / (BPB * 256))

// d_ws layout:
//   gh      : BATCH * BPB * NUM_BINS uint   (2 MB)  per-block partial hists
//   partial : BATCH floats
//   counter : 1 uint
#define GH_ELEMS (BATCH * BPB * NUM_BINS)

typedef float f4 __attribute__((ext_vector_type(4)));

// ---------------------------------------------------------------------------
// Kernel 1: per-block partial histograms (plain coalesced stores, no init).
// Cross-kernel visibility comes from the kernel boundary (implicit release),
// which R3/R5 showed is cheaper than agent fences (full-L2 writeback x2048)
// or 524K device-scope atomics (coherence-point funnel).
// R6: nontemporal loads for the 96 MiB read-once image stream (don't thrash
// L2/L3 — gh and the harness fills want them); clamps dropped (inputs are
// in [-1,1) by construction so (v*0.5+0.5)*255 is already in [0,255); the
// arithmetic expression is kept bit-identical to the passing version).
// ---------------------------------------------------------------------------
__global__ __launch_bounds__(256) void hist_kernel(
    const float* __restrict__ img, unsigned int* __restrict__ gh,
    unsigned int* __restrict__ counter) {
  __shared__ unsigned int lh[4][NUM_BINS];
  const int tid  = threadIdx.x;
  const int wave = tid >> 6;
  const int blk  = blockIdx.x;
  const int b    = blockIdx.y;

  if (blk == 0 && b == 0 && tid == 0) *counter = 0u;

  for (int i = tid; i < 4 * NUM_BINS; i += 256)
    ((unsigned int*)lh)[i] = 0u;
  __syncthreads();

  const f4* src = (const f4*)(img + (size_t)b * CHW);
  int i = blk * 256 + tid;
#pragma unroll 4
  for (int it = 0; it < ITERS; ++it, i += BPB * 256) {
    f4 v = __builtin_nontemporal_load(&src[i]);
    int i0 = (int)((v.x * 0.5f + 0.5f) * 255.0f);
    int i1 = (int)((v.y * 0.5f + 0.5f) * 255.0f);
    int i2 = (int)((v.z * 0.5f + 0.5f) * 255.0f);
    int i3 = (int)((v.w * 0.5f + 0.5f) * 255.0f);
    atomicAdd(&lh[wave][i0], 1u);
    atomicAdd(&lh[wave][i1], 1u);
    atomicAdd(&lh[wave][i2], 1u);
    atomicAdd(&lh[wave][i3], 1u);
  }
  __syncthreads();

  // fold 4 private copies -> one plain coalesced store per bin
  if (tid < NUM_BINS) {
    unsigned int s = lh[0][tid] + lh[1][tid] + lh[2][tid] + lh[3][tid];
    gh[((size_t)b * BPB + blk) * NUM_BINS + tid] = s;
  }
}

// ---------------------------------------------------------------------------
// Kernel 2: per-batch loss + fused final reduction (last-block pattern).
// gen_cdf - tgt_cdf == inclusive_scan(p_gen - p_tgt); sum(gen_hist) == CHW
// exactly (and CHW + 1e-8 == CHW in fp32), so only the target sum reduces.
// R6: 512 threads — two threads per bin each sum 32 of the 64 per-block
// partials (halves the latency-exposed load chain of this 32-block,
// latency-bound kernel), LDS-combine, then the original 256-thread scan
// path (waves 4-7 carry exact zeros through it — harmless).
// ---------------------------------------------------------------------------
__global__ __launch_bounds__(512) void loss_kernel(
    const unsigned int* __restrict__ gh, const float* __restrict__ tgt,
    float* __restrict__ partial, unsigned int* __restrict__ counter,
    float* __restrict__ out) {
  __shared__ float gsum[2][NUM_BINS];
  __shared__ float wsum[8];
  __shared__ float wtot[8];
  __shared__ float wabs[8];
  __shared__ int last_flag;
  const int b = blockIdx.x, tid = threadIdx.x;
  const int lane = tid & 63, wave = tid >> 6;
  const int bin = tid & (NUM_BINS - 1);
  const int half = tid >> 8;          // 0 or 1

  // each half sums 32 of the 64 per-block partials for its bin (coalesced)
  float g = 0.0f;
  const unsigned int* gb =
      gh + (size_t)b * BPB * NUM_BINS + (size_t)half * 32 * NUM_BINS + bin;
#pragma unroll 8
  for (int k = 0; k < 32; ++k) g += (float)gb[k * NUM_BINS];
  gsum[half][bin] = g;
  __syncthreads();

  // threads 0..255 take over; waves 4-7 carry zeros (v == 0) through the
  // scan/reduce below, contributing nothing.
  float t = 0.0f, gt = 0.0f;
  if (tid < NUM_BINS) {
    t  = tgt[b * NUM_BINS + bin];
    gt = gsum[0][bin] + gsum[1][bin];
  }

  // wave reduction of sum(t)  (waves 4-7 produce 0)
  float st = t;
#pragma unroll
  for (int off = 32; off > 0; off >>= 1) st += __shfl_down(st, off);
  if (lane == 0) wsum[wave] = st;
  __syncthreads();
  float stT = wsum[0] + wsum[1] + wsum[2] + wsum[3];

  float v = gt / (float)CHW - t / (stT + 1e-8f);   // == 0 for waves 4-7

  // inclusive scan: shfl within wave, LDS wave offsets
  float sv = v;
#pragma unroll
  for (int off = 1; off < 64; off <<= 1) {
    float n = __shfl_up(sv, off);
    if (lane >= off) sv += n;
  }
  if (lane == 63) wtot[wave] = sv;
  __syncthreads();
  float prefix = 0.0f;
  for (int w = 0; w < wave && w < 4; ++w) prefix += wtot[w];
  sv += prefix;

  // reduce sum |cdf diff|  (waves 4-7: sv == 0 -> a == 0)
  float a = (tid < NUM_BINS) ? fabsf(sv) : 0.0f;
#pragma unroll
  for (int off = 32; off > 0; off >>= 1) a += __shfl_down(a, off);
  if (lane == 0) wabs[wave] = a;
  __syncthreads();

  if (tid == 0) {
    float tot = wabs[0] + wabs[1] + wabs[2] + wabs[3];
    atomicExch(&partial[b], tot);       // device-scope publish
    __threadfence();                    // only 32 of these total — cheap
    unsigned int old = atomicAdd(counter, 1u);
    last_flag = (old == BATCH - 1) ? 1 : 0;
  }
  __syncthreads();

  // last block: reduce the 32 partials to the scalar mean
  if (last_flag && wave == 0) {
    float pv = (lane < BATCH) ? atomicAdd(&partial[lane], 0.0f) : 0.0f;
#pragma unroll
    for (int off = 32; off > 0; off >>= 1) pv += __shfl_down(pv, off);
    if (lane == 0) out[0] = pv / (float)(BATCH * NUM_BINS);
  }
}

extern "C" void kernel_launch(void* const* d_in, const int* in_sizes, int n_in,
                              void* d_out, int out_size, void* d_ws, size_t ws_size,
                              hipStream_t stream) {
  const float* img = (const float*)d_in[0];
  const float* tgt = (const float*)d_in[1];
  float* out = (float*)d_out;

  unsigned int* gh = (unsigned int*)d_ws;
  float* partial = (float*)((char*)d_ws + GH_ELEMS * sizeof(unsigned int));
  unsigned int* counter = (unsigned int*)(partial + BATCH);

  dim3 hgrid(BPB, BATCH, 1);
  hist_kernel<<<hgrid, 256, 0, stream>>>(img, gh, counter);
  loss_kernel<<<BATCH, 512, 0, stream>>>(gh, tgt, partial, counter, out);
}